// Round 9
// baseline (2157.371 us; speedup 1.0000x reference)
//
#include <hip/hip_runtime.h>

// 2-layer GRU (TF GRUCell) + dense via bf16 MFMA, NB=32, 32x32x16 MFMA.
// R9 = R8 register-dieted under the 256-reg (arch+acc unified) cliff:
//  - gate accumulators stay in AGPRs across phases (sigm applied at use);
//    no rr/uu/g2v fp32 arrays.
//  - h_old packed as u32 (bf16hi||bf16lo), not fp32.
//  - all weight pipes depth D=4.
// Structure: NB=32 (128 blocks), h1 state only in A2, layer2 wave role split
// (waves 0-3: u2+c2, waves 4-7: r2), LGKM-only barriers, XOR swizzle.

typedef unsigned short u16;
typedef unsigned int u32;
typedef __attribute__((ext_vector_type(8))) short bhalf8;   // 8 bf16
typedef __attribute__((ext_vector_type(8))) short short8;
typedef __attribute__((ext_vector_type(16))) float fx16;

constexpr int Bc = 4096, Tc = 64, Fc = 32, U1 = 256, U2 = 128;
constexpr int K1 = Fc + U1;   // 288
constexpr int K2 = U1 + U2;   // 384
constexpr int NB = 32, NTHR = 512;
constexpr int NBLK = Bc / NB;  // 128 blocks
constexpr int LDX = 40;        // A1x row stride (u16)
constexpr int LD2 = 384;       // A2 row stride (u16), multiple of 64

constexpr int nW1g = K1 * 512, nW1c = K1 * 256, nW2g = K2 * 256, nW2c = K2 * 128;
constexpr int oW1g = 0;
constexpr int oW1c = oW1g + nW1g;
constexpr int oW2g = oW1c + nW1c;
constexpr int oW2c = oW2g + nW2g;
constexpr int WTOT = oW2c + nW2c;   // 368640 u16
constexpr int nWdT = Fc * U2;       // 4096 floats

#define LGKM_BARRIER() asm volatile("s_waitcnt lgkmcnt(0)\n\ts_barrier" ::: "memory")

__device__ __forceinline__ u16 bf16_rne(float x) {
  unsigned u = __float_as_uint(x);
  return (u16)((u + 0x7fffu + ((u >> 16) & 1u)) >> 16);
}
__device__ __forceinline__ float bf16_f(u16 h) {
  return __uint_as_float(((unsigned)h) << 16);
}
__device__ __forceinline__ float up32(u32 p) {          // unpack hi||lo -> fp32 sum
  return bf16_f((u16)(p >> 16)) + bf16_f((u16)(p & 0xffffu));
}
__device__ __forceinline__ float sigm(float x) { return 1.0f / (1.0f + __expf(-x)); }
__device__ __forceinline__ float tanh_(float x) {
  x = fminf(fmaxf(x, -15.0f), 15.0f);
  const float s = __expf(2.0f * x);
  return (s - 1.0f) / (s + 1.0f);
}

// ---- prep: W[K][N] fp32 -> WT[N][K] bf16; Wd[128][32] -> WdT fp32 ----
__global__ void prep_weights(const float* __restrict__ W1g, const float* __restrict__ W1c,
                             const float* __restrict__ W2g, const float* __restrict__ W2c,
                             const float* __restrict__ Wd, u16* __restrict__ ws) {
  int j = blockIdx.x * 256 + threadIdx.x;
  if (j >= WTOT + nWdT) return;
  if (j >= WTOT) {
    const int jj = j - WTOT;           // jj = o*128 + c
    float* wdT = (float*)(ws + WTOT);
    const int o = jj >> 7, c = jj & 127;
    wdT[jj] = Wd[c * Fc + o];
    return;
  }
  const float* src; u16* dst; int K, N, jj;
  if (j < nW1g)                    { src = W1g; K = K1; N = 512; jj = j;                      dst = ws + oW1g; }
  else if (j < nW1g + nW1c)        { src = W1c; K = K1; N = 256; jj = j - nW1g;               dst = ws + oW1c; }
  else if (j < nW1g + nW1c + nW2g) { src = W2g; K = K2; N = 256; jj = j - nW1g - nW1c;        dst = ws + oW2g; }
  else                             { src = W2c; K = K2; N = 128; jj = j - nW1g - nW1c - nW2g; dst = ws + oW2c; }
  int n = jj / K, k = jj - n * K;
  dst[(size_t)n * K + k] = bf16_rne(src[(size_t)k * N + n]);
}

// Rolling-register weight pipe; unit = one K=16 half (16B/lane B-fragment).
template <int NT, int D, int KH>
struct Pipe {
  const u16* wp[NT];
  bhalf8 bb[D][NT];
  __device__ __forceinline__ void init(const u16* __restrict__ W, const int* n0,
                                       int K, int cl, int ko) {
#pragma unroll
    for (int i = 0; i < NT; ++i) wp[i] = W + (size_t)(n0[i] + cl) * K + ko;
  }
  __device__ __forceinline__ void prefetch() {
#pragma unroll
    for (int d = 0; d < D; ++d)
#pragma unroll
      for (int i = 0; i < NT; ++i) bb[d][i] = *(const bhalf8*)(wp[i] + d * 16);
  }
  __device__ __forceinline__ void roll(int kh) {
    if (kh + D < KH) {
#pragma unroll
      for (int i = 0; i < NT; ++i) bb[kh % D][i] = *(const bhalf8*)(wp[i] + (kh + D) * 16);
    }
  }
};

__global__ __launch_bounds__(NTHR, 1)
void gru_mfma(const float* __restrict__ frames, const u16* __restrict__ ws,
              const float* __restrict__ b1g, const float* __restrict__ b1c,
              const float* __restrict__ b2g, const float* __restrict__ b2c,
              const float* __restrict__ bd, float* __restrict__ out) {
  // A2: [32][LD2]; cols 0..255 = h1 / r*h1 / h1n; cols 256..383 = h2 / r2*h2
  __shared__ alignas(16) u16 A2h_s[32 * LD2], A2l_s[32 * LD2];
  __shared__ alignas(16) u16 A1xh[32 * LDX], A1xl[32 * LDX];   // x_t hi/lo

  const int tid = threadIdx.x;
  const int w = tid >> 6;          // wave 0..7
  const int l = tid & 63;
  const int cl = l & 31;           // A row / output col within tile
  const int hi = l >> 5;
  const int ko = hi * 8;           // per-lane K offset within a K=16 half
  const int b0 = blockIdx.x * NB;

  const int col1 = w * 32 + cl;                 // layer1 output col (0..255 per r/u)
  const int w2 = (w < 4) ? w : (w - 4);
  const int col2 = w2 * 32 + cl;                // layer2 col (0..127)

  const float bR  = b1g[col1];
  const float bU  = b1g[256 + col1];
  const float bC1 = b1c[col1];
  const float bG2 = (w < 4) ? b2g[128 + col2] : b2g[col2];   // u2 : r2
  const float bC2 = b2c[col2];

  Pipe<2, 4, 18> pG1;  Pipe<1, 4, 18> pC1;  Pipe<1, 4, 24> pG2;  Pipe<1, 4, 24> pC2;
  const int n0g1[2] = {w * 32, 256 + w * 32};
  const int n0c1[1] = {w * 32};
  const int n0g2[1] = {(w < 4) ? (128 + w * 32) : ((w - 4) * 32)};
  const int n0c2[1] = {w2 * 32};
  pG1.init(ws + oW1g, n0g1, K1, cl, ko);
  pC1.init(ws + oW1c, n0c1, K1, cl, ko);
  pG2.init(ws + oW2g, n0g2, K2, cl, ko);
  pC2.init(ws + oW2c, n0c2, K2, cl, ko);

  for (int i = tid; i < 32 * LD2; i += NTHR) { A2h_s[i] = 0; A2l_s[i] = 0; }
  for (int i = tid; i < 32 * LDX; i += NTHR) { A1xh[i] = 0; A1xl[i] = 0; }

  const int xb = tid >> 4;              // 0..31
  const int xf0 = (tid & 15) * 2;       // 0,2,..,30
  const float* fptr = frames + (size_t)(b0 + xb) * (Tc * Fc) + xf0;

  {
    const float2 x0 = *(const float2*)(fptr);
    const u16 h0 = bf16_rne(x0.x), h1v = bf16_rne(x0.y);
    const u16 l0 = bf16_rne(x0.x - bf16_f(h0)), l1v = bf16_rne(x0.y - bf16_f(h1v));
    const int idx = xb * LDX + xf0;
    *(u32*)&A1xh[idx] = (u32)h0 | ((u32)h1v << 16);
    *(u32*)&A1xl[idx] = (u32)l0 | ((u32)l1v << 16);
  }
  pG1.prefetch();
  LGKM_BARRIER();

  auto ldA1 = [&](int kh, bhalf8& ah, bhalf8& al) {
    if (kh < 2) {
      const int idx = cl * LDX + kh * 16 + ko;
      ah = *(const bhalf8*)&A1xh[idx];
      al = *(const bhalf8*)&A1xl[idx];
    } else {
      const int c = kh * 16 - 32 + ko;
      const int idx = cl * LD2 + (c ^ ((cl & 7) << 3));
      ah = *(const bhalf8*)&A2h_s[idx];
      al = *(const bhalf8*)&A2l_s[idx];
    }
  };
  auto ldA2 = [&](int kh, bhalf8& ah, bhalf8& al) {
    const int c = kh * 16 + ko;
    const int idx = cl * LD2 + (c ^ ((cl & 7) << 3));
    ah = *(const bhalf8*)&A2h_s[idx];
    al = *(const bhalf8*)&A2l_s[idx];
  };
  auto ew = [&](int row, int col) { return row * LD2 + (col ^ ((row & 7) << 3)); };

  for (int t = 0; t < Tc; ++t) {
    const float2 xn = (t + 1 < Tc) ? *(const float2*)(fptr + (t + 1) * Fc)
                                   : make_float2(0.0f, 0.0f);

    // ---- G1: [x|h1] @ W1g -> aR (r), aU (u) ----
    fx16 aR, aU;
#pragma unroll
    for (int j = 0; j < 16; ++j) { aR[j] = bR; aU[j] = bU; }
#pragma unroll
    for (int kh = 0; kh < 18; ++kh) {
      bhalf8 ah, al; ldA1(kh, ah, al);
      aR = __builtin_amdgcn_mfma_f32_32x32x16_bf16(ah, pG1.bb[kh % 4][0], aR, 0, 0, 0);
      aR = __builtin_amdgcn_mfma_f32_32x32x16_bf16(al, pG1.bb[kh % 4][0], aR, 0, 0, 0);
      aU = __builtin_amdgcn_mfma_f32_32x32x16_bf16(ah, pG1.bb[kh % 4][1], aU, 0, 0, 0);
      aU = __builtin_amdgcn_mfma_f32_32x32x16_bf16(al, pG1.bb[kh % 4][1], aU, 0, 0, 0);
      pG1.roll(kh);
    }
    pC1.prefetch();

    u32 holdp[16];   // packed h1_old (hi||lo), stable until post-B2 writes
#pragma unroll
    for (int j = 0; j < 16; ++j) {
      const int row = (j & 3) + 8 * (j >> 2) + 4 * hi;
      const int idx = ew(row, col1);
      holdp[j] = ((u32)A2h_s[idx] << 16) | (u32)A2l_s[idx];
    }
    LGKM_BARRIER();  // B2: G1 reads of A2/A1x done
#pragma unroll
    for (int j = 0; j < 16; ++j) {
      const int row = (j & 3) + 8 * (j >> 2) + 4 * hi;
      const int idx = ew(row, col1);
      const float rh = sigm(aR[j]) * up32(holdp[j]);   // aR dies here
      const u16 hh = bf16_rne(rh);
      A2h_s[idx] = hh;
      A2l_s[idx] = bf16_rne(rh - bf16_f(hh));
    }
    LGKM_BARRIER();  // B3: r*h1 visible

    // ---- C1: [x|r*h1] @ W1c ----  (aU stays live in acc regs)
    fx16 aC;
#pragma unroll
    for (int j = 0; j < 16; ++j) aC[j] = bC1;
#pragma unroll
    for (int kh = 0; kh < 18; ++kh) {
      bhalf8 ah, al; ldA1(kh, ah, al);
      aC = __builtin_amdgcn_mfma_f32_32x32x16_bf16(ah, pC1.bb[kh % 4][0], aC, 0, 0, 0);
      aC = __builtin_amdgcn_mfma_f32_32x32x16_bf16(al, pC1.bb[kh % 4][0], aC, 0, 0, 0);
      pC1.roll(kh);
    }
    pG2.prefetch();

    u32 hnp[16];   // packed h1_new
#pragma unroll
    for (int j = 0; j < 16; ++j) {
      const float c = tanh_(aC[j]);
      const float hn = c + sigm(aU[j]) * (up32(holdp[j]) - c);
      const u16 hh = bf16_rne(hn);
      hnp[j] = ((u32)hh << 16) | (u32)bf16_rne(hn - bf16_f(hh));
    }
    LGKM_BARRIER();  // B4: C1 reads of A2/A1x done
#pragma unroll
    for (int j = 0; j < 16; ++j) {
      const int row = (j & 3) + 8 * (j >> 2) + 4 * hi;
      const int idx = ew(row, col1);
      A2h_s[idx] = (u16)(hnp[j] >> 16);
      A2l_s[idx] = (u16)(hnp[j] & 0xffffu);
    }
    // stage x_{t+1} (A1x last read by C1)
    {
      const u16 h0 = bf16_rne(xn.x), h1v = bf16_rne(xn.y);
      const u16 l0 = bf16_rne(xn.x - bf16_f(h0)), l1v = bf16_rne(xn.y - bf16_f(h1v));
      const int idx = xb * LDX + xf0;
      *(u32*)&A1xh[idx] = (u32)h0 | ((u32)h1v << 16);
      *(u32*)&A1xl[idx] = (u32)l0 | ((u32)l1v << 16);
    }
    LGKM_BARRIER();  // B5: h1n + x_{t+1} visible

    // ---- G2: [h1n|h2] @ W2g -> waves 0-3: u2 (a2 stays live); 4-7: r2 ----
    fx16 a2;
#pragma unroll
    for (int j = 0; j < 16; ++j) a2[j] = bG2;
#pragma unroll
    for (int kh = 0; kh < 24; ++kh) {
      bhalf8 ah, al; ldA2(kh, ah, al);
      a2 = __builtin_amdgcn_mfma_f32_32x32x16_bf16(ah, pG2.bb[kh % 4][0], a2, 0, 0, 0);
      a2 = __builtin_amdgcn_mfma_f32_32x32x16_bf16(al, pG2.bb[kh % 4][0], a2, 0, 0, 0);
      pG2.roll(kh);
    }
    if (w < 4) pC2.prefetch();

    u32 hold2p[16];
#pragma unroll
    for (int j = 0; j < 16; ++j) {
      const int row = (j & 3) + 8 * (j >> 2) + 4 * hi;
      const int idx = ew(row, 256 + col2);
      hold2p[j] = ((u32)A2h_s[idx] << 16) | (u32)A2l_s[idx];
    }
    LGKM_BARRIER();  // B6: G2 reads of A2 done
    if (w >= 4) {
#pragma unroll
      for (int j = 0; j < 16; ++j) {
        const int row = (j & 3) + 8 * (j >> 2) + 4 * hi;
        const int idx = ew(row, 256 + col2);
        const float rh = sigm(a2[j]) * up32(hold2p[j]);
        const u16 hh = bf16_rne(rh);
        A2h_s[idx] = hh;
        A2l_s[idx] = bf16_rne(rh - bf16_f(hh));
      }
    }
    LGKM_BARRIER();  // B7: r2*h2 visible

    // ---- C2: [h1n|r2*h2] @ W2c (waves 0-3; a2 = u2 logits still live) ----
    fx16 aC2;
#pragma unroll
    for (int j = 0; j < 16; ++j) aC2[j] = bC2;
    if (w < 4) {
#pragma unroll
      for (int kh = 0; kh < 24; ++kh) {
        bhalf8 ah, al; ldA2(kh, ah, al);
        aC2 = __builtin_amdgcn_mfma_f32_32x32x16_bf16(ah, pC2.bb[kh % 4][0], aC2, 0, 0, 0);
        aC2 = __builtin_amdgcn_mfma_f32_32x32x16_bf16(al, pC2.bb[kh % 4][0], aC2, 0, 0, 0);
        pC2.roll(kh);
      }
    }
    pG1.prefetch();            // next step's G1 weights fly across tail barriers
    LGKM_BARRIER();  // B8: C2 reads of A2 done
    if (w < 4) {
#pragma unroll
      for (int j = 0; j < 16; ++j) {
        const int row = (j & 3) + 8 * (j >> 2) + 4 * hi;
        const int idx = ew(row, 256 + col2);
        const float c = tanh_(aC2[j]);
        const float hn = c + sigm(a2[j]) * (up32(hold2p[j]) - c);
        const u16 hh = bf16_rne(hn);
        A2h_s[idx] = hh;                      // h2 for t+1 (and final out)
        A2l_s[idx] = bf16_rne(hn - bf16_f(hh));
      }
    }
    LGKM_BARRIER();  // loop: h2n visible
  }

  // ---- dense: out[b][o] = bd[o] + h2[b] . Wd[:,o]  (WdT fp32 in ws) ----
  {
    const float* wdT = (const float*)(ws + WTOT);   // [32][128]
    const int o = tid & 31, bq = tid >> 5;          // rows bq and bq+16
    float accA = bd[o], accB = bd[o];
#pragma unroll 4
    for (int c8 = 0; c8 < 16; ++c8) {
      const int c = c8 * 8;
      const int ia = ew(bq, 256 + c);
      const int ib = ew(bq + 16, 256 + c);
      const short8 vhA = *(const short8*)&A2h_s[ia];
      const short8 vlA = *(const short8*)&A2l_s[ia];
      const short8 vhB = *(const short8*)&A2h_s[ib];
      const short8 vlB = *(const short8*)&A2l_s[ib];
#pragma unroll
      for (int j = 0; j < 8; ++j) {
        const float wv = wdT[o * 128 + c + j];
        accA = fmaf(bf16_f((u16)vhA[j]) + bf16_f((u16)vlA[j]), wv, accA);
        accB = fmaf(bf16_f((u16)vhB[j]) + bf16_f((u16)vlB[j]), wv, accB);
      }
    }
    out[(size_t)(b0 + bq) * Fc + o] = accA;
    out[(size_t)(b0 + bq + 16) * Fc + o] = accB;
  }
}

extern "C" void kernel_launch(void* const* d_in, const int* in_sizes, int n_in,
                              void* d_out, int out_size, void* d_ws, size_t ws_size,
                              hipStream_t stream) {
  const float* frames = (const float*)d_in[0];
  const float* W1g = (const float*)d_in[1];
  const float* b1g = (const float*)d_in[2];
  const float* W1c = (const float*)d_in[3];
  const float* b1c = (const float*)d_in[4];
  const float* W2g = (const float*)d_in[5];
  const float* b2g = (const float*)d_in[6];
  const float* W2c = (const float*)d_in[7];
  const float* b2c = (const float*)d_in[8];
  const float* Wd  = (const float*)d_in[9];
  const float* bd  = (const float*)d_in[10];
  u16* ws = (u16*)d_ws;
  float* outp = (float*)d_out;

  hipLaunchKernelGGL(prep_weights, dim3((WTOT + nWdT + 255) / 256), dim3(256), 0, stream,
                     W1g, W1c, W2g, W2c, Wd, ws);
  hipLaunchKernelGGL(gru_mfma, dim3(NBLK), dim3(NTHR), 0, stream,
                     frames, ws, b1g, b1c, b2g, b2c, bd, outp);
}

// Round 10
// 947.488 us; speedup vs baseline: 2.2769x; 2.2769x over previous
//
#include <hip/hip_runtime.h>

// 2-layer GRU (TF GRUCell) + dense via bf16 MFMA.
// R10 = R5 base (NB=16, 16x16x32 MFMA, hi/lo activations, bf16 weights,
// LGKM-only barriers, cross-phase register prefetch) with the 9-barrier step
// restructured to 4 barriers: r*h1 and r2*h2 go to SEPARATE RH buffers, so
// the WAR barrier pairs around in-place h overwrites disappear.
//   G1 mm -> write RH1 -- a -- C1 mm -> write h1n -- b -- G2 mm -> write RH2,
//   stage x(t+1) -- g -- C2 mm -> write h2n -- d
// NB=32 abandoned: R6-R9 all spilled loop-invariants (arch budget ~128 when
// accs occupy the unified file's other half; FETCH 1.5GB read >> write).

typedef unsigned short u16;
typedef unsigned int u32;
typedef __attribute__((ext_vector_type(8))) short bhalf8;   // 8 bf16
typedef __attribute__((ext_vector_type(4))) float fx4;

constexpr int Bc = 4096, Tc = 64, Fc = 32, U1 = 256, U2 = 128;
constexpr int K1 = Fc + U1;   // 288
constexpr int K2 = U1 + U2;   // 384
constexpr int NB = 16, NTHR = 512;
constexpr int LD1 = 296;      // A1 row stride (u16): 592B, 2-way banks
constexpr int LD2 = 392;      // A2 row stride: 784B
constexpr int LDR1 = 264;     // RH1 row stride: 528B
constexpr int LDR2 = 136;     // RH2 row stride: 272B

// d_ws layout: u16 transposed bf16 weights, then fp32 WdT[32][128].
constexpr int nW1g = K1 * 512, nW1c = K1 * 256, nW2g = K2 * 256, nW2c = K2 * 128;
constexpr int oW1g = 0;
constexpr int oW1c = oW1g + nW1g;
constexpr int oW2g = oW1c + nW1c;
constexpr int oW2c = oW2g + nW2g;
constexpr int WTOT = oW2c + nW2c;   // 368640 u16
constexpr int nWdT = Fc * U2;       // 4096 floats

// dynamic LDS layout (u16 units)
constexpr int oA1h = 0;
constexpr int oA1l = oA1h + 16 * LD1;
constexpr int oA2h = oA1l + 16 * LD1;
constexpr int oA2l = oA2h + 16 * LD2;
constexpr int oR1h = oA2l + 16 * LD2;
constexpr int oR1l = oR1h + 16 * LDR1;
constexpr int oR2h = oR1l + 16 * LDR1;
constexpr int oR2l = oR2h + 16 * LDR2;
constexpr int SM_TOT = oR2l + 16 * LDR2;          // 34816 u16
constexpr size_t SMEM_BYTES = (size_t)SM_TOT * 2; // 69632 B

#define LGKM_BARRIER() asm volatile("s_waitcnt lgkmcnt(0)\n\ts_barrier" ::: "memory")

__device__ __forceinline__ u16 bf16_rne(float x) {
  unsigned u = __float_as_uint(x);
  return (u16)((u + 0x7fffu + ((u >> 16) & 1u)) >> 16);
}
__device__ __forceinline__ float bf16_f(u16 h) {
  return __uint_as_float(((unsigned)h) << 16);
}
__device__ __forceinline__ float sigm(float x) { return 1.0f / (1.0f + __expf(-x)); }
__device__ __forceinline__ float tanh_(float x) {
  x = fminf(fmaxf(x, -15.0f), 15.0f);
  const float s = __expf(2.0f * x);
  return (s - 1.0f) / (s + 1.0f);
}

// ---- prep: W[K][N] fp32 -> WT[N][K] bf16; Wd[128][32] -> WdT fp32 ----
__global__ void prep_weights(const float* __restrict__ W1g, const float* __restrict__ W1c,
                             const float* __restrict__ W2g, const float* __restrict__ W2c,
                             const float* __restrict__ Wd, u16* __restrict__ ws) {
  int j = blockIdx.x * 256 + threadIdx.x;
  if (j >= WTOT + nWdT) return;
  if (j >= WTOT) {
    const int jj = j - WTOT;           // jj = o*128 + c
    float* wdT = (float*)(ws + WTOT);
    const int o = jj >> 7, c = jj & 127;
    wdT[jj] = Wd[c * Fc + o];
    return;
  }
  const float* src; u16* dst; int K, N, jj;
  if (j < nW1g)                    { src = W1g; K = K1; N = 512; jj = j;                      dst = ws + oW1g; }
  else if (j < nW1g + nW1c)        { src = W1c; K = K1; N = 256; jj = j - nW1g;               dst = ws + oW1c; }
  else if (j < nW1g + nW1c + nW2g) { src = W2g; K = K2; N = 256; jj = j - nW1g - nW1c;        dst = ws + oW2g; }
  else                             { src = W2c; K = K2; N = 128; jj = j - nW1g - nW1c - nW2g; dst = ws + oW2c; }
  int n = jj / K, k = jj - n * K;
  dst[(size_t)n * K + k] = bf16_rne(src[(size_t)k * N + n]);
}

// Rolling-register weight pipe (unit = K-group of 32, 16B/lane fragment).
template <int NT, int D, int KT>
struct Pipe {
  const u16* wp[NT];
  bhalf8 bb[D][NT];
  __device__ __forceinline__ void init(const u16* __restrict__ W, const int* n0,
                                       int K, int lc, int ao) {
#pragma unroll
    for (int i = 0; i < NT; ++i) wp[i] = W + (size_t)(n0[i] + lc) * K + ao;
  }
  __device__ __forceinline__ void prefetch() {
#pragma unroll
    for (int d = 0; d < D; ++d)
#pragma unroll
      for (int i = 0; i < NT; ++i) bb[d][i] = *(const bhalf8*)(wp[i] + d * 32);
  }
  __device__ __forceinline__ void roll(int kt) {
    if (kt + D < KT) {
#pragma unroll
      for (int i = 0; i < NT; ++i) bb[kt % D][i] = *(const bhalf8*)(wp[i] + (kt + D) * 32);
    }
  }
};

template <int NT, int D, int KT, typename P, typename LD>
__device__ __forceinline__ void run_mm(P& p, fx4 (&acc)[NT], LD&& ld) {
#pragma unroll
  for (int kt = 0; kt < KT; ++kt) {
    bhalf8 ah, al;
    ld(kt, ah, al);
#pragma unroll
    for (int i = 0; i < NT; ++i) {
      acc[i] = __builtin_amdgcn_mfma_f32_16x16x32_bf16(ah, p.bb[kt % D][i], acc[i], 0, 0, 0);
      acc[i] = __builtin_amdgcn_mfma_f32_16x16x32_bf16(al, p.bb[kt % D][i], acc[i], 0, 0, 0);
    }
    p.roll(kt);
  }
}

__global__ __launch_bounds__(NTHR, 2)
void gru_mfma(const float* __restrict__ frames, const u16* __restrict__ ws,
              const float* __restrict__ b1g, const float* __restrict__ b1c,
              const float* __restrict__ b2g, const float* __restrict__ b2c,
              const float* __restrict__ bd, float* __restrict__ out) {
  extern __shared__ u16 sm[];

  const int tid = threadIdx.x;
  const int w = tid >> 6;          // wave 0..7
  const int l = tid & 63;
  const int lc = l & 15;           // col-in-tile / A row
  const int lk = l >> 4;
  const int ao = lk * 8;
  const int row0 = lk * 4;
  const int b0 = blockIdx.x * NB;

  const float bg1r0 = b1g[w * 32 + lc],       bg1r1 = b1g[w * 32 + 16 + lc];
  const float bg1u0 = b1g[256 + w * 32 + lc], bg1u1 = b1g[256 + w * 32 + 16 + lc];
  const float bc10  = b1c[w * 32 + lc],       bc11  = b1c[w * 32 + 16 + lc];
  const float bg2r  = b2g[w * 16 + lc],       bg2u  = b2g[128 + w * 16 + lc];
  const float bc2v  = b2c[w * 16 + lc];

  Pipe<4, 4, 9> pG1;  Pipe<2, 6, 9> pC1;  Pipe<2, 6, 12> pG2;  Pipe<1, 8, 12> pC2;
  const int n0g1[4] = {w * 32, w * 32 + 16, 256 + w * 32, 256 + w * 32 + 16};
  const int n0c1[2] = {w * 32, w * 32 + 16};
  const int n0g2[2] = {w * 16, 128 + w * 16};
  const int n0c2[1] = {w * 16};
  pG1.init(ws + oW1g, n0g1, K1, lc, ao);
  pC1.init(ws + oW1c, n0c1, K1, lc, ao);
  pG2.init(ws + oW2g, n0g2, K2, lc, ao);
  pC2.init(ws + oW2c, n0c2, K2, lc, ao);

  for (int i = tid; i < SM_TOT; i += NTHR) sm[i] = 0;

  const int xb = tid >> 5, xf = tid & 31;
  const float* fptr = frames + (size_t)(b0 + xb) * (Tc * Fc) + xf;

  // prologue: stage x_0, prefetch G1
  {
    const float x0 = fptr[0];
    const u16 h = bf16_rne(x0);
    sm[oA1h + xb * LD1 + xf] = h;
    sm[oA1l + xb * LD1 + xf] = bf16_rne(x0 - bf16_f(h));
  }
  pG1.prefetch();
  LGKM_BARRIER();

  // A-fragment loaders (A row = lc)
  auto ldG1 = [&](int kt, bhalf8& ah, bhalf8& al) {        // A1 = [x | h1]
    const int idx = lc * LD1 + kt * 32 + ao;
    ah = *(const bhalf8*)&sm[oA1h + idx];
    al = *(const bhalf8*)&sm[oA1l + idx];
  };
  auto ldC1 = [&](int kt, bhalf8& ah, bhalf8& al) {        // [x | RH1]
    if (kt == 0) {
      const int idx = lc * LD1 + ao;
      ah = *(const bhalf8*)&sm[oA1h + idx];
      al = *(const bhalf8*)&sm[oA1l + idx];
    } else {
      const int idx = lc * LDR1 + (kt - 1) * 32 + ao;
      ah = *(const bhalf8*)&sm[oR1h + idx];
      al = *(const bhalf8*)&sm[oR1l + idx];
    }
  };
  auto ldG2 = [&](int kt, bhalf8& ah, bhalf8& al) {        // A2 = [h1n | h2]
    const int idx = lc * LD2 + kt * 32 + ao;
    ah = *(const bhalf8*)&sm[oA2h + idx];
    al = *(const bhalf8*)&sm[oA2l + idx];
  };
  auto ldC2 = [&](int kt, bhalf8& ah, bhalf8& al) {        // [h1n | RH2]
    if (kt < 8) {
      const int idx = lc * LD2 + kt * 32 + ao;
      ah = *(const bhalf8*)&sm[oA2h + idx];
      al = *(const bhalf8*)&sm[oA2l + idx];
    } else {
      const int idx = lc * LDR2 + (kt - 8) * 32 + ao;
      ah = *(const bhalf8*)&sm[oR2h + idx];
      al = *(const bhalf8*)&sm[oR2l + idx];
    }
  };

  for (int t = 0; t < Tc; ++t) {
    const float xn = (t + 1 < Tc) ? fptr[(t + 1) * Fc] : 0.0f;

    // ==== G1: [x|h1] @ W1g -> r,u ====
    fx4 acc[4] = { {bg1r0, bg1r0, bg1r0, bg1r0}, {bg1r1, bg1r1, bg1r1, bg1r1},
                   {bg1u0, bg1u0, bg1u0, bg1u0}, {bg1u1, bg1u1, bg1u1, bg1u1} };
    run_mm<4, 4, 9>(pG1, acc, ldG1);
    pC1.prefetch();

    float hold1[2][4], uu[2][4];
#pragma unroll
    for (int i = 0; i < 2; ++i)
#pragma unroll
      for (int q = 0; q < 4; ++q) {
        const int row = row0 + q, col = w * 32 + i * 16 + lc;
        hold1[i][q] = bf16_f(sm[oA1h + row * LD1 + Fc + col]) +
                      bf16_f(sm[oA1l + row * LD1 + Fc + col]);
        uu[i][q] = sigm(acc[2 + i][q]);
      }
#pragma unroll
    for (int i = 0; i < 2; ++i)
#pragma unroll
      for (int q = 0; q < 4; ++q) {
        const int row = row0 + q, col = w * 32 + i * 16 + lc;
        const float rh = sigm(acc[i][q]) * hold1[i][q];
        const u16 hh = bf16_rne(rh);
        sm[oR1h + row * LDR1 + col] = hh;
        sm[oR1l + row * LDR1 + col] = bf16_rne(rh - bf16_f(hh));
      }
    LGKM_BARRIER();  // a: RH1 ready (G1 reads of A1 done)

    // ==== C1: [x|r*h1] @ W1c -> h1n ====
    fx4 accc[2] = { {bc10, bc10, bc10, bc10}, {bc11, bc11, bc11, bc11} };
    run_mm<2, 6, 9>(pC1, accc, ldC1);
    pG2.prefetch();

#pragma unroll
    for (int i = 0; i < 2; ++i)
#pragma unroll
      for (int q = 0; q < 4; ++q) {
        const int row = row0 + q, col = w * 32 + i * 16 + lc;
        const float c = tanh_(accc[i][q]);
        const float hn = c + uu[i][q] * (hold1[i][q] - c);
        const u16 hh = bf16_rne(hn);
        const u16 hl = bf16_rne(hn - bf16_f(hh));
        sm[oA1h + row * LD1 + Fc + col] = hh;   // h1 state for t+1
        sm[oA1l + row * LD1 + Fc + col] = hl;
        sm[oA2h + row * LD2 + col] = hh;        // layer2 input
        sm[oA2l + row * LD2 + col] = hl;
      }
    LGKM_BARRIER();  // b: h1n ready (C1 reads of x/RH1 done)

    // ==== G2: [h1n|h2] @ W2g -> r2,u2 ====
    fx4 acc2[2] = { {bg2r, bg2r, bg2r, bg2r}, {bg2u, bg2u, bg2u, bg2u} };
    run_mm<2, 6, 12>(pG2, acc2, ldG2);
    pC2.prefetch();

    float hold2[4], uu2[4];
#pragma unroll
    for (int q = 0; q < 4; ++q) {
      const int row = row0 + q, col = w * 16 + lc;
      hold2[q] = bf16_f(sm[oA2h + row * LD2 + U1 + col]) +
                 bf16_f(sm[oA2l + row * LD2 + U1 + col]);
      uu2[q] = sigm(acc2[1][q]);
    }
#pragma unroll
    for (int q = 0; q < 4; ++q) {
      const int row = row0 + q, col = w * 16 + lc;
      const float rh = sigm(acc2[0][q]) * hold2[q];
      const u16 hh = bf16_rne(rh);
      sm[oR2h + row * LDR2 + col] = hh;
      sm[oR2l + row * LDR2 + col] = bf16_rne(rh - bf16_f(hh));
    }
    // stage x_{t+1} (C1 readers of A1x finished before barrier b)
    {
      const u16 h = bf16_rne(xn);
      sm[oA1h + xb * LD1 + xf] = h;
      sm[oA1l + xb * LD1 + xf] = bf16_rne(xn - bf16_f(h));
    }
    LGKM_BARRIER();  // g: RH2 + x_{t+1} ready (G2 reads of A2 done)

    // ==== C2: [h1n|r2*h2] @ W2c -> h2n ====
    fx4 acc3[1] = { {bc2v, bc2v, bc2v, bc2v} };
    run_mm<1, 8, 12>(pC2, acc3, ldC2);
    pG1.prefetch();            // next step's G1 weights in flight across d

#pragma unroll
    for (int q = 0; q < 4; ++q) {
      const int row = row0 + q, col = w * 16 + lc;
      const float c = tanh_(acc3[0][q]);
      const float hn = c + uu2[q] * (hold2[q] - c);
      const u16 hh = bf16_rne(hn);
      sm[oA2h + row * LD2 + U1 + col] = hh;       // h2 for t+1 (and final out)
      sm[oA2l + row * LD2 + U1 + col] = bf16_rne(hn - bf16_f(hh));
    }
    LGKM_BARRIER();  // d: h2n ready
  }

  // ---- dense: out[b][o] = bd[o] + h2[b] . Wd[:,o]  (WdT fp32 in ws) ----
  {
    const float* wdT = (const float*)(ws + WTOT);   // [32][128]
    const int o = tid & 31, b = tid >> 5;
    const float4* wrow = (const float4*)(wdT + o * 128);
    float acc = bd[o];
#pragma unroll 8
    for (int c4 = 0; c4 < 32; ++c4) {
      const float4 wv = wrow[c4];
      const int c = c4 * 4;
      const int base = b * LD2 + U1 + c;
      const float h0 = bf16_f(sm[oA2h + base + 0]) + bf16_f(sm[oA2l + base + 0]);
      const float h1 = bf16_f(sm[oA2h + base + 1]) + bf16_f(sm[oA2l + base + 1]);
      const float h2 = bf16_f(sm[oA2h + base + 2]) + bf16_f(sm[oA2l + base + 2]);
      const float h3 = bf16_f(sm[oA2h + base + 3]) + bf16_f(sm[oA2l + base + 3]);
      acc = fmaf(h0, wv.x, fmaf(h1, wv.y, fmaf(h2, wv.z, fmaf(h3, wv.w, acc))));
    }
    out[(size_t)(b0 + b) * Fc + o] = acc;
  }
}

extern "C" void kernel_launch(void* const* d_in, const int* in_sizes, int n_in,
                              void* d_out, int out_size, void* d_ws, size_t ws_size,
                              hipStream_t stream) {
  const float* frames = (const float*)d_in[0];
  const float* W1g = (const float*)d_in[1];
  const float* b1g = (const float*)d_in[2];
  const float* W1c = (const float*)d_in[3];
  const float* b1c = (const float*)d_in[4];
  const float* W2g = (const float*)d_in[5];
  const float* b2g = (const float*)d_in[6];
  const float* W2c = (const float*)d_in[7];
  const float* b2c = (const float*)d_in[8];
  const float* Wd  = (const float*)d_in[9];
  const float* bd  = (const float*)d_in[10];
  u16* ws = (u16*)d_ws;
  float* outp = (float*)d_out;

  hipFuncSetAttribute(reinterpret_cast<const void*>(gru_mfma),
                      hipFuncAttributeMaxDynamicSharedMemorySize, (int)SMEM_BYTES);

  hipLaunchKernelGGL(prep_weights, dim3((WTOT + nWdT + 255) / 256), dim3(256), 0, stream,
                     W1g, W1c, W2g, W2c, Wd, ws);
  hipLaunchKernelGGL(gru_mfma, dim3(Bc / NB), dim3(NTHR), SMEM_BYTES, stream,
                     frames, ws, b1g, b1c, b2g, b2c, bd, outp);
}